// Round 1
// baseline (90.797 us; speedup 1.0000x reference)
//
#include <hip/hip_runtime.h>
#include <math.h>

// Problem constants (fixed by setup_inputs): bs=16, Q=300, C=2, P=320
#define BS 16
#define QN 300
#define CN 2
#define PN 320
#define NN (BS * QN)   // 4800 queries
#define KPRED 53       // pred_kpts row length
#define KTGT 54        // tgt_kpts row length
#define TILE_N 8       // query rows per block -> 600 blocks

// One block: 320 threads (thread = target index p), processes TILE_N query rows.
// Target features live in per-thread registers for the whole n-loop; pred
// features are wave-uniform loads recomputed per row (uniform VALU, cheap).
__global__ __launch_bounds__(PN) void hungarian_cost_kernel(
    const float* __restrict__ pred_logits,  // [N, 2]
    const float* __restrict__ pred_kpts,    // [N, 53]
    const float* __restrict__ tgt_kpts,     // [P, 54]
    const int*   __restrict__ tgt_ids,      // [P]
    float* __restrict__ out)                // [N, P]
{
    const int p  = threadIdx.x;       // target index, 0..319
    const int n0 = blockIdx.x * TILE_N;

    // ---- per-thread target features (registers) ----
    float tx[18], ty[18], vis[18];
    float tidk[17];
    {
        const float* t = tgt_kpts + (size_t)p * KTGT;
        #pragma unroll
        for (int j = 0; j < 18; ++j) {
            tx[j]  = t[3 * j];
            ty[j]  = t[3 * j + 1];
            vis[j] = (t[3 * j + 2] == 1.0f) ? 1.0f : 0.0f;
        }
        #pragma unroll
        for (int j = 0; j < 17; ++j) tidk[j] = t[5 + 3 * j];
    }
    const int cls = tgt_ids[p];  // 0 or 1

    for (int ni = 0; ni < TILE_N; ++ni) {
        const int n = n0 + ni;

        // ---- wave-uniform pred features ----
        const float l0 = pred_logits[n * CN + 0];
        const float l1 = pred_logits[n * CN + 1];
        const float m  = fmaxf(l0, l1);
        const float e0 = expf(l0 - m);
        const float e1 = expf(l1 - m);
        const float inv = 1.0f / (e0 + e1);
        const float p0 = e0 * inv, p1 = e1 * inv;

        float k[KPRED];
        {
            const float* kp = pred_kpts + (size_t)n * KPRED;
            #pragma unroll
            for (int i = 0; i < KPRED; ++i) k[i] = kp[i];
        }
        // x = [k0, k2, k5, ..., k50]; y = [k1, k3, k6, ..., k51]
        float x[18], y[18];
        x[0] = k[0]; y[0] = k[1];
        #pragma unroll
        for (int j = 1; j < 18; ++j) { x[j] = k[3 * j - 1]; y[j] = k[3 * j]; }

        const float dx0 = x[0] - tx[0];
        const float dy0 = y[0] - ty[0];

        float cd = 0.0f;   // cost_deltas
        float ck = 0.0f;   // cost_kpts (abs coords): xa-txa = 2*dx + dx0
        #pragma unroll
        for (int j = 1; j < 18; ++j) {
            const float dx = x[j] - tx[j];
            const float dy = y[j] - ty[j];
            cd = fmaf(vis[j], fabsf(dx) + fabsf(dy), cd);
            const float ax = fmaf(2.0f, dx, dx0);
            const float ay = fmaf(2.0f, dy, dy0);
            ck = fmaf(vis[j], fabsf(ax) + fabsf(ay), ck);
        }

        // cost_kpts_class: L2 over 17 dims, pred k[4::3] vs tgt t[5::3]
        float cq = 0.0f;
        #pragma unroll
        for (int j = 0; j < 17; ++j) {
            const float d = k[4 + 3 * j] - tidk[j];
            cq = fmaf(d, d, cq);
        }
        const float ckc = sqrtf(cq);

        // cost_ctrs: L2 on joint 0, masked by vis[0]
        const float cx = dx0 * vis[0];
        const float cy = dy0 * vis[0];
        const float cc = sqrtf(cx * cx + cy * cy);

        // cost_class = -softmax(logits)[cls]
        const float ccls = -((cls == 0) ? p0 : p1);

        out[(size_t)n * PN + p] = ck + cc + cd + ccls + ckc;
    }
}

extern "C" void kernel_launch(void* const* d_in, const int* in_sizes, int n_in,
                              void* d_out, int out_size, void* d_ws, size_t ws_size,
                              hipStream_t stream) {
    const float* pred_logits = (const float*)d_in[0];  // 16*300*2
    const float* pred_kpts   = (const float*)d_in[1];  // 16*300*53
    const float* tgt_kpts    = (const float*)d_in[2];  // 320*54
    const int*   tgt_ids     = (const int*)d_in[3];    // 320
    float* out = (float*)d_out;                        // 16*300*320

    dim3 grid(NN / TILE_N);   // 600 blocks
    dim3 block(PN);           // 320 threads
    hipLaunchKernelGGL(hungarian_cost_kernel, grid, block, 0, stream,
                       pred_logits, pred_kpts, tgt_kpts, tgt_ids, out);
}

// Round 2
// 74.418 us; speedup vs baseline: 1.2201x; 1.2201x over previous
//
#include <hip/hip_runtime.h>
#include <math.h>

// Problem constants (fixed by setup_inputs): bs=16, Q=300, C=2, P=320
#define BS 16
#define QN 300
#define CN 2
#define PN 320
#define NN (BS * QN)   // 4800 query rows
#define KPRED 53
#define KTGT 54
#define TILE_N 4       // query rows per block -> 1200 blocks

// thread = target p (0..319, 5 waves/block); block handles TILE_N query rows.
// Target features in registers for the whole block. Key register trick:
// tgt_kpts[:,5::3] (kpts-class vec) aliases the vis slots [:,2::3] shifted by
// one joint, so one raw w[] array serves both; vis itself is a bitmask.
__global__ __launch_bounds__(PN) void hungarian_cost_kernel(
    const float* __restrict__ pred_logits,  // [N, 2]
    const float* __restrict__ pred_kpts,    // [N, 53]
    const float* __restrict__ tgt_kpts,     // [P, 54]
    const int*   __restrict__ tgt_ids,      // [P]
    float* __restrict__ out)                // [N, P]
{
    const int p  = threadIdx.x;
    const int n0 = blockIdx.x * TILE_N;

    // ---- per-thread target features ----
    float tx[18], ty[18], w[18];   // w[j] = t[3j+2] raw (vis slot / class tgt)
    unsigned vmask = 0u;
    {
        const float* t = tgt_kpts + (size_t)p * KTGT;
        #pragma unroll
        for (int j = 0; j < 18; ++j) {
            tx[j] = t[3 * j];
            ty[j] = t[3 * j + 1];
            const float vv = t[3 * j + 2];
            w[j] = vv;
            vmask |= (vv == 1.0f) ? (1u << j) : 0u;
        }
    }
    const int cls = tgt_ids[p];

    // logits for all TILE_N rows, one batched (uniform -> SMEM) load
    float lg[2 * TILE_N];
    #pragma unroll
    for (int i = 0; i < 2 * TILE_N; ++i) lg[i] = pred_logits[n0 * CN + i];

    #pragma unroll
    for (int ni = 0; ni < TILE_N; ++ni) {
        const int n = n0 + ni;

        float k[KPRED];   // wave-uniform -> compiler keeps in SGPRs
        {
            const float* kp = pred_kpts + (size_t)n * KPRED;
            #pragma unroll
            for (int i = 0; i < KPRED; ++i) k[i] = kp[i];
        }

        const float dx0 = k[0] - tx[0];
        const float dy0 = k[1] - ty[0];

        float cd = 0.0f;   // cost_deltas
        float ck = 0.0f;   // cost_kpts: xa - txa = 2*dx + dx0
        float cq = 0.0f;   // kpts-class squared distance
        #pragma unroll
        for (int j = 1; j < 18; ++j) {
            const float vj = (float)((vmask >> j) & 1u);
            const float dx = k[3 * j - 1] - tx[j];
            const float dy = k[3 * j]     - ty[j];
            cd = fmaf(vj, fabsf(dx) + fabsf(dy), cd);
            const float ax = fmaf(2.0f, dx, dx0);
            const float ay = fmaf(2.0f, dy, dy0);
            ck = fmaf(vj, fabsf(ax) + fabsf(ay), ck);
            const float d = k[3 * j + 1] - w[j];   // tid[j-1] == w[j]
            cq = fmaf(d, d, cq);
        }

        // cost_ctrs = vis0 * ||(dx0, dy0)||
        const float v0 = (float)(vmask & 1u);
        const float cc = v0 * sqrtf(fmaf(dx0, dx0, dy0 * dy0));

        // cost_class = -softmax(logits)[cls]
        const float l0 = lg[2 * ni], l1 = lg[2 * ni + 1];
        const float m  = fmaxf(l0, l1);
        const float e0 = __expf(l0 - m);
        const float e1 = __expf(l1 - m);
        const float inv = 1.0f / (e0 + e1);
        const float ccls = -((cls == 0) ? e0 : e1) * inv;

        out[(size_t)n * PN + p] = ck + cc + cd + ccls + sqrtf(cq);
    }
}

extern "C" void kernel_launch(void* const* d_in, const int* in_sizes, int n_in,
                              void* d_out, int out_size, void* d_ws, size_t ws_size,
                              hipStream_t stream) {
    const float* pred_logits = (const float*)d_in[0];
    const float* pred_kpts   = (const float*)d_in[1];
    const float* tgt_kpts    = (const float*)d_in[2];
    const int*   tgt_ids     = (const int*)d_in[3];
    float* out = (float*)d_out;

    dim3 grid(NN / TILE_N);   // 1200 blocks
    dim3 block(PN);           // 320 threads = 5 waves
    hipLaunchKernelGGL(hungarian_cost_kernel, grid, block, 0, stream,
                       pred_logits, pred_kpts, tgt_kpts, tgt_ids, out);
}